// Round 2
// baseline (393.230 us; speedup 1.0000x reference)
//
#include <hip/hip_runtime.h>
#include <stdint.h>

#define E_TOTAL 100000
#define B_TOTAL 8
#define CIN 32
#define COUT 64
#define TILES 1563  // ceil(E_TOTAL/64)

typedef short bf16x8 __attribute__((ext_vector_type(8)));
typedef float f32x4  __attribute__((ext_vector_type(4)));
typedef int   i32x4  __attribute__((ext_vector_type(4)));
typedef unsigned u32x4 __attribute__((ext_vector_type(4)));

union U16x8 { u32x4 u; bf16x8 s; };

// ---- bf16 pair helpers (2 bf16 packed in one uint) ----
__device__ inline float blo(unsigned u) { return __uint_as_float(u << 16); }
__device__ inline float bhi(unsigned u) { return __uint_as_float(u & 0xffff0000u); }
__device__ inline unsigned bpack(float lo, float hi) {
    return (__float_as_uint(lo) >> 16) | (__float_as_uint(hi) & 0xffff0000u);
}
__device__ inline unsigned badd(unsigned a, unsigned b) {
    return bpack(blo(a) + blo(b), bhi(a) + bhi(b));
}
__device__ inline unsigned babsdiff(unsigned a, unsigned b) {
    return bpack(fabsf(blo(a) - blo(b)), fabsf(bhi(a) - bhi(b)));
}
__device__ inline u32x4 vadd4(u32x4 a, u32x4 b) {
    u32x4 r;
#pragma unroll
    for (int i = 0; i < 4; i++) r[i] = badd(a[i], b[i]);
    return r;
}
__device__ inline u32x4 vabsdiff4(u32x4 a, u32x4 b) {
    u32x4 r;
#pragma unroll
    for (int i = 0; i < 4; i++) r[i] = babsdiff(a[i], b[i]);
    return r;
}
// round-to-nearest-even fp32 -> bf16
__device__ inline unsigned rne16(float f) {
    unsigned b = __float_as_uint(f);
    b += 0x7fffu + ((b >> 16) & 1u);
    return b >> 16;
}

// ---- kernel 1: fused weight-prep + x transpose/cast ----
// blocks [0, TILES*8): x (B,C,E) fp32 -> xt (B,E,32) bf16 via LDS tile
// block TILES*8: repack weight (64,32,1,5) fp32 -> MFMA-B-fragment bf16:
//   wb shorts at ((t*5+g)*64 + lane)*8 + j  =  W[o=(lane&15)+16t][c=(lane>>4)*8+j][g]
__global__ __launch_bounds__(256) void prep_transpose(
    const float* __restrict__ x, unsigned* __restrict__ xt,
    const float* __restrict__ w, unsigned short* __restrict__ wb) {
    const int tid = threadIdx.x;
    if (blockIdx.x >= TILES * 8) {
        for (int idx = tid; idx < 4 * 5 * 64 * 8; idx += 256) {
            int j = idx & 7;
            int lane = (idx >> 3) & 63;
            int tg = idx >> 9;
            int g = tg % 5;
            int t = tg / 5;
            int n = lane & 15, qq = lane >> 4;
            int o = n + 16 * t;
            int c = qq * 8 + j;
            wb[idx] = (unsigned short)rne16(w[(o * CIN + c) * 5 + g]);
        }
        return;
    }
    __shared__ float tbuf[CIN][65];
    const int b = blockIdx.x & 7;            // batch -> XCD affinity
    const int e0 = (blockIdx.x >> 3) * 64;
    const int el = tid & 63;
    const int cw = tid >> 6;                 // 0..3
#pragma unroll
    for (int i = 0; i < 8; i++) {
        int c = cw * 8 + i;
        int e = e0 + el;
        float v = (e < E_TOTAL)
            ? __builtin_nontemporal_load(x + ((size_t)b * CIN + c) * E_TOTAL + e)
            : 0.f;
        tbuf[c][el] = v;
    }
    __syncthreads();
    const int c2 = tid & 15;                 // bf16-pair index (16 pairs = 32 ch)
#pragma unroll
    for (int i = 0; i < 4; i++) {
        int el2 = (tid >> 4) * 4 + i;
        int e = e0 + el2;
        if (e < E_TOTAL) {
            unsigned lo = rne16(tbuf[c2 * 2][el2]);
            unsigned hi = rne16(tbuf[c2 * 2 + 1][el2]);
            xt[((size_t)b * E_TOTAL + e) * 16 + c2] = lo | (hi << 16);
        }
    }
}

// ---- kernel 2: gather + symmetric functions + MFMA GEMM ----
__global__ __launch_bounds__(256) void meshconv_main(
    const unsigned short* __restrict__ xt,   // (B,E,32) bf16
    const int* __restrict__ ge,              // (B,E,4)
    const u32x4* __restrict__ wb,            // 1280 frag-ready weight quads (20 KB)
    const float* __restrict__ bias,          // (64)
    float* __restrict__ out) {               // (B,64,E) fp32
    __shared__ u32x4 wlds[1280];             // 20 KB
    const int tid = threadIdx.x;
    const int lane = tid & 63;
    const int wv = tid >> 6;
    const int b = blockIdx.x & 7;            // batch -> XCD affinity
    const int tile = blockIdx.x >> 3;
    const int e0 = tile * 64 + wv * 16;
    const int n = lane & 15;                 // A: edge row; B/D: o-within-tile
    const int q = lane >> 4;
    const bool active = (e0 < E_TOTAL);      // E%16==0: active waves are full
    const int em = active ? (e0 + n) : 0;

    // issue index + self-row loads early; they complete during LDS staging
    i32x4 nid = __builtin_nontemporal_load(
        (const i32x4*)(ge + ((size_t)b * E_TOTAL + em) * 4));
    const unsigned short* xb = xt + (size_t)b * E_TOTAL * CIN;
    const int co = q * 8;
    u32x4 a0 = *(const u32x4*)(xb + (size_t)em * CIN + co);

    // stage weight fragments to LDS (keeps VGPR low -> occupancy for gather latency)
#pragma unroll
    for (int k = 0; k < 5; k++) wlds[tid + k * 256] = wb[tid + k * 256];
    __syncthreads();

    // random neighbor gathers: one 64 B row (one cache line) each
    u32x4 a1 = *(const u32x4*)(xb + (size_t)nid[0] * CIN + co);
    u32x4 a2 = *(const u32x4*)(xb + (size_t)nid[1] * CIN + co);
    u32x4 a3 = *(const u32x4*)(xb + (size_t)nid[2] * CIN + co);
    u32x4 a4 = *(const u32x4*)(xb + (size_t)nid[3] * CIN + co);

    u32x4 A[5];
    A[0] = a0;
    A[1] = vadd4(a1, a3);
    A[2] = vadd4(a2, a4);
    A[3] = vabsdiff4(a1, a3);
    A[4] = vabsdiff4(a2, a4);

    f32x4 acc[4];
#pragma unroll
    for (int t = 0; t < 4; t++)
#pragma unroll
        for (int r = 0; r < 4; r++) acc[t][r] = 0.f;

#pragma unroll
    for (int g = 0; g < 5; g++) {
        U16x8 av; av.u = A[g];
#pragma unroll
        for (int t = 0; t < 4; t++) {
            U16x8 bv; bv.u = wlds[(t * 5 + g) * 64 + lane];
            acc[t] = __builtin_amdgcn_mfma_f32_16x16x32_bf16(av.s, bv.s, acc[t], 0, 0, 0);
        }
    }

    // D: col(o)=lane&15, row(e)=q*4+reg -> lane holds 4 consecutive e.
    // float4 store: 4 lanes (q=0..3) of one n cover 64 consecutive B = full lines.
    // nontemporal: output is write-once; keep L2 for the gather working set.
    if (active) {
#pragma unroll
        for (int t = 0; t < 4; t++) {
            const int o = n + 16 * t;
            f32x4 r = acc[t] + bias[o];
            __builtin_nontemporal_store(
                r, (f32x4*)(out + ((size_t)b * COUT + o) * E_TOTAL + e0 + q * 4));
        }
    }
}

// ---- fallback (insufficient scratch): direct fp32, slow but correct ----
__global__ __launch_bounds__(256) void meshconv_fallback(
    const float* __restrict__ x, const int* __restrict__ ge,
    const float* __restrict__ w, const float* __restrict__ bias,
    float* __restrict__ out) {
    __shared__ float f[5][32];
    __shared__ float G[5][32];
    __shared__ int idxs[4];
    const int e = blockIdx.x, b = blockIdx.y;
    const int tid = threadIdx.x;
    if (tid < 4) idxs[tid] = ge[((size_t)b * E_TOTAL + e) * 4 + tid];
    __syncthreads();
    if (tid < 160) {
        int k = tid >> 5, c = tid & 31;
        int src = (k == 0) ? e : idxs[k - 1];
        f[k][c] = x[((size_t)b * CIN + c) * E_TOTAL + src];
    }
    __syncthreads();
    if (tid < 32) {
        int c = tid;
        G[0][c] = f[0][c];
        G[1][c] = f[1][c] + f[3][c];
        G[2][c] = f[2][c] + f[4][c];
        G[3][c] = fabsf(f[1][c] - f[3][c]);
        G[4][c] = fabsf(f[2][c] - f[4][c]);
    }
    __syncthreads();
    if (tid < COUT) {
        float acc = bias[tid];
        for (int c = 0; c < CIN; c++)
#pragma unroll
            for (int g = 0; g < 5; g++)
                acc += G[g][c] * w[(tid * CIN + c) * 5 + g];
        out[((size_t)b * COUT + tid) * E_TOTAL + e] = acc;
    }
}

extern "C" void kernel_launch(void* const* d_in, const int* in_sizes, int n_in,
                              void* d_out, int out_size, void* d_ws, size_t ws_size,
                              hipStream_t stream) {
    const float* x = (const float*)d_in[0];
    const int* ge = (const int*)d_in[1];
    const float* w = (const float*)d_in[2];
    const float* bias = (const float*)d_in[3];
    float* out = (float*)d_out;

    const size_t xt_bytes = (size_t)B_TOTAL * E_TOTAL * CIN * 2;  // 51.2 MB
    const size_t need = 65536 + xt_bytes;
    if (ws_size < need) {
        dim3 grid(E_TOTAL, B_TOTAL);
        meshconv_fallback<<<grid, 256, 0, stream>>>(x, ge, w, bias, out);
        return;
    }
    unsigned short* wb = (unsigned short*)d_ws;
    unsigned short* xt = (unsigned short*)((char*)d_ws + 65536);

    prep_transpose<<<TILES * 8 + 1, 256, 0, stream>>>(x, (unsigned*)xt, w, wb);
    meshconv_main<<<TILES * 8, 256, 0, stream>>>(xt, ge, (const u32x4*)wb, bias, out);
}

// Round 3
// 373.977 us; speedup vs baseline: 1.0515x; 1.0515x over previous
//
#include <hip/hip_runtime.h>
#include <stdint.h>

#define E_TOTAL 100000
#define B_TOTAL 8
#define CIN 32
#define COUT 64
#define TILES 1563   // ceil(E_TOTAL/64) for transpose
#define NUNITS 782   // ceil(E_TOTAL/128): 128-e units for main (block covers 4 waves x 32 e)
#define NBLK 256     // blocks per batch in main (grid = 8*NBLK)

typedef short bf16x8 __attribute__((ext_vector_type(8)));
typedef float f32x4  __attribute__((ext_vector_type(4)));
typedef int   i32x4  __attribute__((ext_vector_type(4)));
typedef unsigned u32x4 __attribute__((ext_vector_type(4)));

union U16x8 { u32x4 u; bf16x8 s; };

// ---- bf16 pair helpers (2 bf16 packed in one uint) ----
__device__ inline float blo(unsigned u) { return __uint_as_float(u << 16); }
__device__ inline float bhi(unsigned u) { return __uint_as_float(u & 0xffff0000u); }
__device__ inline unsigned bpack(float lo, float hi) {
    return (__float_as_uint(lo) >> 16) | (__float_as_uint(hi) & 0xffff0000u);
}
__device__ inline unsigned badd(unsigned a, unsigned b) {
    return bpack(blo(a) + blo(b), bhi(a) + bhi(b));
}
__device__ inline unsigned babsdiff(unsigned a, unsigned b) {
    return bpack(fabsf(blo(a) - blo(b)), fabsf(bhi(a) - bhi(b)));
}
__device__ inline u32x4 vadd4(u32x4 a, u32x4 b) {
    u32x4 r;
#pragma unroll
    for (int i = 0; i < 4; i++) r[i] = badd(a[i], b[i]);
    return r;
}
__device__ inline u32x4 vabsdiff4(u32x4 a, u32x4 b) {
    u32x4 r;
#pragma unroll
    for (int i = 0; i < 4; i++) r[i] = babsdiff(a[i], b[i]);
    return r;
}
// round-to-nearest-even fp32 -> bf16
__device__ inline unsigned rne16(float f) {
    unsigned b = __float_as_uint(f);
    b += 0x7fffu + ((b >> 16) & 1u);
    return b >> 16;
}

// ---- kernel 1: fused weight-prep + x transpose/cast ----
__global__ __launch_bounds__(256) void prep_transpose(
    const float* __restrict__ x, unsigned* __restrict__ xt,
    const float* __restrict__ w, unsigned short* __restrict__ wb) {
    const int tid = threadIdx.x;
    if (blockIdx.x >= TILES * 8) {
        for (int idx = tid; idx < 4 * 5 * 64 * 8; idx += 256) {
            int j = idx & 7;
            int lane = (idx >> 3) & 63;
            int tg = idx >> 9;
            int g = tg % 5;
            int t = tg / 5;
            int nn = lane & 15, qq = lane >> 4;
            int o = nn + 16 * t;
            int c = qq * 8 + j;
            wb[idx] = (unsigned short)rne16(w[(o * CIN + c) * 5 + g]);
        }
        return;
    }
    __shared__ float tbuf[CIN][65];
    const int b = blockIdx.x & 7;            // batch -> XCD affinity
    const int e0 = (blockIdx.x >> 3) * 64;
    const int el = tid & 63;
    const int cw = tid >> 6;
#pragma unroll
    for (int i = 0; i < 8; i++) {
        int c = cw * 8 + i;
        int e = e0 + el;
        float v = (e < E_TOTAL)
            ? __builtin_nontemporal_load(x + ((size_t)b * CIN + c) * E_TOTAL + e)
            : 0.f;
        tbuf[c][el] = v;
    }
    __syncthreads();
    const int c2 = tid & 15;
#pragma unroll
    for (int i = 0; i < 4; i++) {
        int el2 = (tid >> 4) * 4 + i;
        int e = e0 + el2;
        if (e < E_TOTAL) {
            unsigned lo = rne16(tbuf[c2 * 2][el2]);
            unsigned hi = rne16(tbuf[c2 * 2 + 1][el2]);
            xt[((size_t)b * E_TOTAL + e) * 16 + c2] = lo | (hi << 16);
        }
    }
}

// ---- kernel 2: gather + symmetric functions + MFMA GEMM ----
// Block-strided over 128-e units; each wave does 32 e (two 16x16x32 A-tiles)
// per iteration -> 10 independent 64 B row-gathers in flight; next unit's
// indices/self-rows prefetched during current unit's MFMA.
__global__ __launch_bounds__(256) void meshconv_main(
    const unsigned short* __restrict__ xt,   // (B,E,32) bf16
    const int* __restrict__ ge,              // (B,E,4)
    const u32x4* __restrict__ wb,            // frag-ready weights (20 KB)
    const float* __restrict__ bias,          // (64)
    float* __restrict__ out) {               // (B,64,E) fp32
    __shared__ u32x4 wlds[1280];
    const int tid = threadIdx.x;
    const int lane = tid & 63;
    const int wv = tid >> 6;
    const int b = blockIdx.x & 7;            // batch -> XCD affinity
    const int blk = blockIdx.x >> 3;
    const int n = lane & 15;
    const int q = lane >> 4;
    const int co = q * 8;

#pragma unroll
    for (int k = 0; k < 5; k++) wlds[tid + k * 256] = wb[tid + k * 256];
    __syncthreads();

    const unsigned short* xb = xt + (size_t)b * E_TOTAL * CIN;
    const int* geb = ge + (size_t)b * E_TOTAL * 4;
    float bv[4];
#pragma unroll
    for (int t = 0; t < 4; t++) bv[t] = bias[n + 16 * t];

    // prologue: unit u's indices + self rows
    int u = blk;
    int e0 = u * 128 + wv * 32;
    bool act = (u < NUNITS) && (e0 < E_TOTAL);   // E%32==0: full waves only
    i32x4 nid0, nid1;
    u32x4 s0, s1;
    if (act) {
        nid0 = __builtin_nontemporal_load((const i32x4*)(geb + (size_t)(e0 + n) * 4));
        nid1 = __builtin_nontemporal_load((const i32x4*)(geb + (size_t)(e0 + 16 + n) * 4));
        s0 = *(const u32x4*)(xb + (size_t)(e0 + n) * CIN + co);
        s1 = *(const u32x4*)(xb + (size_t)(e0 + 16 + n) * CIN + co);
    }

    for (; u < NUNITS; u += NBLK) {
        const int un = u + NBLK;
        const int e0n = un * 128 + wv * 32;
        const bool actn = (un < NUNITS) && (e0n < E_TOTAL);

        // 8 random row-gathers for current unit (independent, all in flight)
        u32x4 g10, g20, g30, g40, g11, g21, g31, g41;
        if (act) {
            g10 = *(const u32x4*)(xb + (size_t)nid0[0] * CIN + co);
            g20 = *(const u32x4*)(xb + (size_t)nid0[1] * CIN + co);
            g30 = *(const u32x4*)(xb + (size_t)nid0[2] * CIN + co);
            g40 = *(const u32x4*)(xb + (size_t)nid0[3] * CIN + co);
            g11 = *(const u32x4*)(xb + (size_t)nid1[0] * CIN + co);
            g21 = *(const u32x4*)(xb + (size_t)nid1[1] * CIN + co);
            g31 = *(const u32x4*)(xb + (size_t)nid1[2] * CIN + co);
            g41 = *(const u32x4*)(xb + (size_t)nid1[3] * CIN + co);
        }
        // prefetch next unit's indices + self rows (independent of the gathers)
        i32x4 nid0n, nid1n;
        u32x4 s0n, s1n;
        if (actn) {
            nid0n = __builtin_nontemporal_load((const i32x4*)(geb + (size_t)(e0n + n) * 4));
            nid1n = __builtin_nontemporal_load((const i32x4*)(geb + (size_t)(e0n + 16 + n) * 4));
            s0n = *(const u32x4*)(xb + (size_t)(e0n + n) * CIN + co);
            s1n = *(const u32x4*)(xb + (size_t)(e0n + 16 + n) * CIN + co);
        }

        if (act) {
            u32x4 A0[5], A1[5];
            A0[0] = s0;
            A0[1] = vadd4(g10, g30);
            A0[2] = vadd4(g20, g40);
            A0[3] = vabsdiff4(g10, g30);
            A0[4] = vabsdiff4(g20, g40);
            A1[0] = s1;
            A1[1] = vadd4(g11, g31);
            A1[2] = vadd4(g21, g41);
            A1[3] = vabsdiff4(g11, g31);
            A1[4] = vabsdiff4(g21, g41);

            f32x4 acc0[4], acc1[4];
#pragma unroll
            for (int t = 0; t < 4; t++)
#pragma unroll
                for (int r = 0; r < 4; r++) { acc0[t][r] = 0.f; acc1[t][r] = 0.f; }

#pragma unroll
            for (int g = 0; g < 5; g++) {
                U16x8 av0; av0.u = A0[g];
                U16x8 av1; av1.u = A1[g];
#pragma unroll
                for (int t = 0; t < 4; t++) {
                    U16x8 bw; bw.u = wlds[(t * 5 + g) * 64 + lane];
                    acc0[t] = __builtin_amdgcn_mfma_f32_16x16x32_bf16(av0.s, bw.s, acc0[t], 0, 0, 0);
                    acc1[t] = __builtin_amdgcn_mfma_f32_16x16x32_bf16(av1.s, bw.s, acc1[t], 0, 0, 0);
                }
            }

            // per o-row: two adjacent f32x4 stores -> 128 B contiguous per wave
#pragma unroll
            for (int t = 0; t < 4; t++) {
                const int o = n + 16 * t;
                float* orow = out + ((size_t)b * COUT + o) * E_TOTAL + e0 + q * 4;
                f32x4 r0 = acc0[t] + bv[t];
                f32x4 r1 = acc1[t] + bv[t];
                __builtin_nontemporal_store(r0, (f32x4*)orow);
                __builtin_nontemporal_store(r1, (f32x4*)(orow + 16));
            }
        }

        nid0 = nid0n; nid1 = nid1n; s0 = s0n; s1 = s1n;
        e0 = e0n; act = actn;
    }
}

// ---- fallback (insufficient scratch): direct fp32, slow but correct ----
__global__ __launch_bounds__(256) void meshconv_fallback(
    const float* __restrict__ x, const int* __restrict__ ge,
    const float* __restrict__ w, const float* __restrict__ bias,
    float* __restrict__ out) {
    __shared__ float f[5][32];
    __shared__ float G[5][32];
    __shared__ int idxs[4];
    const int e = blockIdx.x, b = blockIdx.y;
    const int tid = threadIdx.x;
    if (tid < 4) idxs[tid] = ge[((size_t)b * E_TOTAL + e) * 4 + tid];
    __syncthreads();
    if (tid < 160) {
        int k = tid >> 5, c = tid & 31;
        int src = (k == 0) ? e : idxs[k - 1];
        f[k][c] = x[((size_t)b * CIN + c) * E_TOTAL + src];
    }
    __syncthreads();
    if (tid < 32) {
        int c = tid;
        G[0][c] = f[0][c];
        G[1][c] = f[1][c] + f[3][c];
        G[2][c] = f[2][c] + f[4][c];
        G[3][c] = fabsf(f[1][c] - f[3][c]);
        G[4][c] = fabsf(f[2][c] - f[4][c]);
    }
    __syncthreads();
    if (tid < COUT) {
        float acc = bias[tid];
        for (int c = 0; c < CIN; c++)
#pragma unroll
            for (int g = 0; g < 5; g++)
                acc += G[g][c] * w[(tid * CIN + c) * 5 + g];
        out[((size_t)b * COUT + tid) * E_TOTAL + e] = acc;
    }
}

extern "C" void kernel_launch(void* const* d_in, const int* in_sizes, int n_in,
                              void* d_out, int out_size, void* d_ws, size_t ws_size,
                              hipStream_t stream) {
    const float* x = (const float*)d_in[0];
    const int* ge = (const int*)d_in[1];
    const float* w = (const float*)d_in[2];
    const float* bias = (const float*)d_in[3];
    float* out = (float*)d_out;

    const size_t xt_bytes = (size_t)B_TOTAL * E_TOTAL * CIN * 2;  // 51.2 MB
    const size_t need = 65536 + xt_bytes;
    if (ws_size < need) {
        dim3 grid(E_TOTAL, B_TOTAL);
        meshconv_fallback<<<grid, 256, 0, stream>>>(x, ge, w, bias, out);
        return;
    }
    unsigned short* wb = (unsigned short*)d_ws;
    unsigned short* xt = (unsigned short*)((char*)d_ws + 65536);

    prep_transpose<<<TILES * 8 + 1, 256, 0, stream>>>(x, (unsigned*)xt, w, wb);
    meshconv_main<<<NBLK * 8, 256, 0, stream>>>(xt, ge, (const u32x4*)wb, bias, out);
}